// Round 13
// baseline (1320.402 us; speedup 1.0000x reference)
//
#include <hip/hip_runtime.h>
#include <hip/hip_bf16.h>

#define DIM 2048
#define INTER 1408
#define NEXP 16
#define NTOK 8192
#define SINTER 2816

typedef __attribute__((ext_vector_type(8))) short bf16x8;
typedef __attribute__((ext_vector_type(4))) float f32x4;
typedef __attribute__((ext_vector_type(4))) unsigned short u16x4;
typedef __attribute__((ext_vector_type(8))) unsigned short u16x8;

#define VMCNT(n) asm volatile("s_waitcnt vmcnt(" #n ")" ::: "memory")
#define BARRIER() __builtin_amdgcn_s_barrier()

__device__ __forceinline__ unsigned short f2bf(float f) {
    union { float f; unsigned u; } a; a.f = f;
    unsigned r = a.u + 0x7fffu + ((a.u >> 16) & 1u);
    return (unsigned short)(r >> 16);
}
__device__ __forceinline__ float bf2f(unsigned short u) {
    union { unsigned u; float f; } a; a.u = ((unsigned)u) << 16; return a.f;
}

__device__ __forceinline__ void gload16(const void* g, void* lds) {
    __builtin_amdgcn_global_load_lds(
        (const __attribute__((address_space(1))) void*)g,
        (__attribute__((address_space(3))) void*)lds, 16, 0, 0);
}

// ---------------- one-shot f32 -> bf16 cast of ALL weight tensors ----------------
__global__ __launch_bounds__(256) void cast_all(
    const float* __restrict__ w1, const float* __restrict__ w3,
    const float* __restrict__ w2, const float* __restrict__ sw1,
    const float* __restrict__ sw3, const float* __restrict__ sw2,
    unsigned short* __restrict__ w1b, unsigned short* __restrict__ w3b,
    unsigned short* __restrict__ w2b, unsigned short* __restrict__ sw1b,
    unsigned short* __restrict__ sw3b, unsigned short* __restrict__ sw2b) {
    const long long NW = (long long)NEXP * INTER * DIM;   // 46,137,344
    const long long NS = (long long)SINTER * DIM;         //  5,767,168
    long long i = ((long long)blockIdx.x * 256 + threadIdx.x) * 8;
    const float* s; unsigned short* d; long long off;
    if      (i < NW)            { s = w1;  d = w1b;  off = i; }
    else if (i < 2 * NW)        { s = w3;  d = w3b;  off = i - NW; }
    else if (i < 3 * NW)        { s = w2;  d = w2b;  off = i - 2 * NW; }
    else if (i < 3 * NW + NS)   { s = sw1; d = sw1b; off = i - 3 * NW; }
    else if (i < 3 * NW + 2*NS) { s = sw3; d = sw3b; off = i - 3 * NW - NS; }
    else if (i < 3 * NW + 3*NS) { s = sw2; d = sw2b; off = i - 3 * NW - 2 * NS; }
    else return;
    float4 a = *(const float4*)(s + off), b = *(const float4*)(s + off + 4);
    u16x8 o = { f2bf(a.x), f2bf(a.y), f2bf(a.z), f2bf(a.w),
                f2bf(b.x), f2bf(b.y), f2bf(b.z), f2bf(b.w) };
    *(u16x8*)(d + off) = o;
}

// ---------------- gate + top2 routing (+ x -> bf16 cast fused) ----------------
__global__ __launch_bounds__(256) void gate_topk(
    const float* __restrict__ x, const float* __restrict__ gw,
    unsigned short* __restrict__ xb,
    int* __restrict__ counts, int* __restrict__ toklist,
    int* __restrict__ se, int* __restrict__ sp, float* __restrict__ swt) {
    int wave = threadIdx.x >> 6;
    int lane = threadIdx.x & 63;
    int tok  = blockIdx.x * 4 + wave;
    const float* xr = x + (size_t)tok * DIM;
    unsigned short* xbr = xb + (size_t)tok * DIM;

    float part[NEXP];
#pragma unroll
    for (int e = 0; e < NEXP; ++e) part[e] = 0.f;
#pragma unroll
    for (int c = 0; c < DIM / 256; ++c) {
        float4 xv = *(const float4*)(xr + c * 256 + lane * 4);
        u16x4 xo = { f2bf(xv.x), f2bf(xv.y), f2bf(xv.z), f2bf(xv.w) };
        *(u16x4*)(xbr + c * 256 + lane * 4) = xo;
#pragma unroll
        for (int e = 0; e < NEXP; ++e) {
            float4 g = *(const float4*)(gw + e * DIM + c * 256 + lane * 4);
            part[e] += xv.x * g.x + xv.y * g.y + xv.z * g.z + xv.w * g.w;
        }
    }
#pragma unroll
    for (int e = 0; e < NEXP; ++e) {
        float v = part[e];
#pragma unroll
        for (int off = 32; off; off >>= 1) v += __shfl_xor(v, off);
        part[e] = v;
    }
    float mx = part[0];
#pragma unroll
    for (int e = 1; e < NEXP; ++e) mx = fmaxf(mx, part[e]);
    float Z = 0.f;
#pragma unroll
    for (int e = 0; e < NEXP; ++e) Z += expf(part[e] - mx);
    int i1 = 0; float m1 = part[0];
#pragma unroll
    for (int e = 1; e < NEXP; ++e) if (part[e] > m1) { m1 = part[e]; i1 = e; }
    int i2 = -1; float m2 = -1e30f;
#pragma unroll
    for (int e = 0; e < NEXP; ++e) if (e != i1 && part[e] > m2) { m2 = part[e]; i2 = e; }
    if (lane == 0) {
        float w1v = expf(m1 - mx) / Z;
        float w2v = expf(m2 - mx) / Z;
        int p1 = atomicAdd(&counts[i1], 1);
        toklist[i1 * NTOK + p1] = tok;
        int p2 = atomicAdd(&counts[i2], 1);
        toklist[i2 * NTOK + p2] = tok;
        se[2 * tok] = i1;  sp[2 * tok] = p1;  swt[2 * tok] = w1v;
        se[2 * tok + 1] = i2;  sp[2 * tok + 1] = p2;  swt[2 * tok + 1] = w2v;
    }
}

__global__ void prefix_k(const int* __restrict__ counts, int* __restrict__ base) {
    if (threadIdx.x == 0) {
        int acc = 0;
        for (int e = 0; e < NEXP; ++e) { base[e] = acc; acc += counts[e]; }
        base[16] = acc;          // == 2*NTOK
        base[17] = acc + NTOK;
    }
}

// ================= GEMM1: h = silu(X W1^T) * (X W3^T) =================
// tile 256x128, BK=64, asymmetric depth: A triple-buffered (96 KB, loads get
// 2 steps of flight), B1/B3 double-buffered (64 KB). 160 KB LDS total.
// Per step: issue B(h+1) then A(h+2); end-wait vmcnt(4) leaves A(h+2) in
// flight (never drains to 0 mid-loop). One barrier/step.
__global__ __launch_bounds__(512, 2) void gemm1(
    const unsigned short* __restrict__ xb,
    const unsigned short* __restrict__ w1b, const unsigned short* __restrict__ w3b,
    const unsigned short* __restrict__ sw1b, const unsigned short* __restrict__ sw3b,
    const int* __restrict__ counts, const int* __restrict__ base,
    const int* __restrict__ toklist, unsigned short* __restrict__ hbuf) {
    const int e   = blockIdx.z;
    const int cnt = (e < NEXP) ? counts[e] : NTOK;
    const int m0  = blockIdx.y * 256;
    if (m0 >= cnt) return;
    const int n0  = blockIdx.x * 128;
    const size_t woff = (size_t)((e < NEXP) ? e : e - NEXP) * INTER * DIM;
    const unsigned short* B1 = ((e < NEXP) ? w1b : sw1b) + woff;
    const unsigned short* B3 = ((e < NEXP) ? w3b : sw3b) + woff;
    const int hbase = base[e];
    const int* tl = toklist + e * NTOK;

    __shared__ __attribute__((aligned(16))) unsigned short As[3][16384];  // 96 KB
    __shared__ __attribute__((aligned(16))) unsigned short B1s[2][8192];  // 32 KB
    __shared__ __attribute__((aligned(16))) unsigned short B3s[2][8192];  // 32 KB

    const int tid = threadIdx.x;
    const int w = tid >> 6, lu = tid & 63;
    const int wr = w >> 1, wc = w & 1;
    const int lr = lu & 15, hi = lu >> 4;

    const int srow = tid >> 3;
    const int sslot = tid & 7;
    const int cEl = ((sslot ^ (srow & 7)) * 8);

    const unsigned short* aSrc[4];
#pragma unroll
    for (int i = 0; i < 4; ++i) {
        int grow = m0 + 64 * i + srow;
        int t;
        if (e < NEXP) t = (grow < cnt) ? tl[grow] : 0;
        else          t = grow;
        aSrc[i] = xb + (size_t)t * DIM + cEl;
    }
    const unsigned short *b1Src[2], *b3Src[2];
#pragma unroll
    for (int i = 0; i < 2; ++i) {
        int r = n0 + 64 * i + srow;
        b1Src[i] = B1 + (size_t)r * DIM + cEl;
        b3Src[i] = B3 + (size_t)r * DIM + cEl;
    }

    int aoff[2][4], boff[2][4];
#pragma unroll
    for (int kk = 0; kk < 2; ++kk) {
#pragma unroll
        for (int m = 0; m < 4; ++m) {
            int R = wr * 64 + m * 16 + lr;
            aoff[kk][m] = R * 128 + (((kk * 4 + hi) ^ (lr & 7)) << 4);
        }
#pragma unroll
        for (int n = 0; n < 4; ++n) {
            int R = wc * 64 + n * 16 + lr;
            boff[kk][n] = R * 128 + (((kk * 4 + hi) ^ (lr & 7)) << 4);
        }
    }

    f32x4 acc1[4][4], acc3[4][4];
#pragma unroll
    for (int m = 0; m < 4; ++m)
#pragma unroll
        for (int n = 0; n < 4; ++n) {
            acc1[m][n] = (f32x4){0.f, 0.f, 0.f, 0.f};
            acc3[m][n] = (f32x4){0.f, 0.f, 0.f, 0.f};
        }

    const int H = DIM / 64;   // 32 steps

    auto STAGE_A = [&](int hh) {
        int ab = hh % 3;
        int kc = hh * 64;
#pragma unroll
        for (int i = 0; i < 4; ++i)
            gload16(aSrc[i] + kc, &As[ab][i * 4096 + tid * 8]);
    };
    auto STAGE_B = [&](int hh) {
        int bb = hh & 1;
        int kc = hh * 64;
#pragma unroll
        for (int i = 0; i < 2; ++i) {
            gload16(b1Src[i] + kc, &B1s[bb][i * 4096 + tid * 8]);
            gload16(b3Src[i] + kc, &B3s[bb][i * 4096 + tid * 8]);
        }
    };

    // prologue: FIFO = A(0)[4], B(0)[4], A(1)[4]; wait A(0)+B(0) -> vmcnt(4)
    STAGE_A(0); STAGE_B(0); STAGE_A(1);
    VMCNT(4);
    BARRIER();

    for (int h = 0; h < H; ++h) {
        // issue next-tiles FIRST (max flight time); order B(h+1) then A(h+2)
        if (h + 2 < H)      { STAGE_B(h + 1); STAGE_A(h + 2); }
        else if (h + 1 < H) { STAGE_B(h + 1); }
        const int ab = h % 3, bb = h & 1;
        const char* As_ = (const char*)&As[ab][0];
        const char* B1_ = (const char*)&B1s[bb][0];
        const char* B3_ = (const char*)&B3s[bb][0];
        bf16x8 af[4], b1f[4], b3f[4];
#pragma unroll
        for (int m = 0; m < 4; ++m) af[m] = *(const bf16x8*)(As_ + aoff[0][m]);
#pragma unroll
        for (int n = 0; n < 4; ++n) {
            b1f[n] = *(const bf16x8*)(B1_ + boff[0][n]);
            b3f[n] = *(const bf16x8*)(B3_ + boff[0][n]);
        }
        __builtin_amdgcn_s_setprio(1);
#pragma unroll
        for (int n = 0; n < 4; ++n)
#pragma unroll
            for (int m = 0; m < 4; ++m)
                acc1[m][n] = __builtin_amdgcn_mfma_f32_16x16x32_bf16(af[m], b1f[n], acc1[m][n], 0, 0, 0);
#pragma unroll
        for (int n = 0; n < 4; ++n)
#pragma unroll
            for (int m = 0; m < 4; ++m)
                acc3[m][n] = __builtin_amdgcn_mfma_f32_16x16x32_bf16(af[m], b3f[n], acc3[m][n], 0, 0, 0);
        __builtin_amdgcn_s_setprio(0);
#pragma unroll
        for (int m = 0; m < 4; ++m) af[m] = *(const bf16x8*)(As_ + aoff[1][m]);
#pragma unroll
        for (int n = 0; n < 4; ++n) {
            b1f[n] = *(const bf16x8*)(B1_ + boff[1][n]);
            b3f[n] = *(const bf16x8*)(B3_ + boff[1][n]);
        }
        __builtin_amdgcn_s_setprio(1);
#pragma unroll
        for (int n = 0; n < 4; ++n)
#pragma unroll
            for (int m = 0; m < 4; ++m)
                acc1[m][n] = __builtin_amdgcn_mfma_f32_16x16x32_bf16(af[m], b1f[n], acc1[m][n], 0, 0, 0);
#pragma unroll
        for (int n = 0; n < 4; ++n)
#pragma unroll
            for (int m = 0; m < 4; ++m)
                acc3[m][n] = __builtin_amdgcn_mfma_f32_16x16x32_bf16(af[m], b3f[n], acc3[m][n], 0, 0, 0);
        __builtin_amdgcn_s_setprio(0);
        // wait: A(h+1) and B(h+1) landed; A(h+2) (newest 4 loads) stays in flight
        if (h + 2 < H) { VMCNT(4); } else { VMCNT(0); }
        BARRIER();
    }

    // epilogue: h = silu(c1)*c3 -> bf16 scratch
#pragma unroll
    for (int m = 0; m < 4; ++m) {
#pragma unroll
        for (int i = 0; i < 4; ++i) {
            int row  = wr * 64 + m * 16 + hi * 4 + i;
            int grow = m0 + row;
            if (grow < cnt) {
                size_t ro = (size_t)(hbase + grow) * INTER;
#pragma unroll
                for (int n = 0; n < 4; ++n) {
                    int col = n0 + wc * 64 + n * 16 + lr;
                    float a = acc1[m][n][i];
                    float hv = a / (1.f + __expf(-a)) * acc3[m][n][i];
                    hbuf[ro + col] = f2bf(hv);
                }
            }
        }
    }
}

// ================= GEMM2: g2buf = h W2^T (linear bf16 rows) =================
// tile 256x256, BK=64, A triple-buffered (96 KB) + B double-buffered (64 KB),
// same asymmetric-depth schedule as gemm1 (vmcnt(4) mid-loop).
__global__ __launch_bounds__(512, 2) void gemm2(
    const unsigned short* __restrict__ hbuf,
    const unsigned short* __restrict__ w2b, const unsigned short* __restrict__ sw2b,
    const int* __restrict__ counts, const int* __restrict__ base,
    unsigned short* __restrict__ g2buf) {
    const int e   = blockIdx.z;
    const int cnt = (e < NEXP) ? counts[e] : NTOK;
    const int m0  = blockIdx.y * 256;
    if (m0 >= cnt) return;
    const int n0  = blockIdx.x * 256;
    const int hbase = base[e];
    const size_t bstride = (e < NEXP) ? INTER : SINTER;
    const unsigned short* Bb = (e < NEXP) ? w2b + (size_t)e * DIM * INTER
                                          : sw2b + (size_t)(e - NEXP) * INTER;

    __shared__ __attribute__((aligned(16))) unsigned short Ah[3][16384];  // 96 KB
    __shared__ __attribute__((aligned(16))) unsigned short Bh[2][16384];  // 64 KB

    const int tid = threadIdx.x;
    const int w = tid >> 6, lu = tid & 63;
    const int wr = w >> 2, wc = w & 3;
    const int lr = lu & 15, hi = lu >> 4;

    const int srow = tid >> 3;
    const int sslot = tid & 7;
    const int cEl = ((sslot ^ (srow & 7)) * 8);

    const unsigned short* aSrc[4];
#pragma unroll
    for (int i = 0; i < 4; ++i)
        aSrc[i] = hbuf + (size_t)(hbase + m0 + 64 * i + srow) * INTER + cEl;
    const unsigned short* bSrc[4];
#pragma unroll
    for (int i = 0; i < 4; ++i)
        bSrc[i] = Bb + (size_t)(n0 + 64 * i + srow) * bstride + cEl;

    int aoff[2][8], boff[2][4];
#pragma unroll
    for (int kk = 0; kk < 2; ++kk) {
#pragma unroll
        for (int m = 0; m < 8; ++m) {
            int R = wr * 128 + m * 16 + lr;
            aoff[kk][m] = R * 128 + (((kk * 4 + hi) ^ (lr & 7)) << 4);
        }
#pragma unroll
        for (int n = 0; n < 4; ++n) {
            int R = wc * 64 + n * 16 + lr;
            boff[kk][n] = R * 128 + (((kk * 4 + hi) ^ (lr & 7)) << 4);
        }
    }

    f32x4 acc[8][4];
#pragma unroll
    for (int m = 0; m < 8; ++m)
#pragma unroll
        for (int n = 0; n < 4; ++n) acc[m][n] = (f32x4){0.f, 0.f, 0.f, 0.f};

    const int H = INTER / 64;   // 22 steps

    auto STAGE_A = [&](int hh) {
        int ab = hh % 3;
        int kc = hh * 64;
#pragma unroll
        for (int i = 0; i < 4; ++i)
            gload16(aSrc[i] + kc, &Ah[ab][i * 4096 + tid * 8]);
    };
    auto STAGE_B = [&](int hh) {
        int bb = hh & 1;
        int kc = hh * 64;
#pragma unroll
        for (int i = 0; i < 4; ++i)
            gload16(bSrc[i] + kc, &Bh[bb][i * 4096 + tid * 8]);
    };

    STAGE_A(0); STAGE_B(0); STAGE_A(1);
    VMCNT(4);
    BARRIER();

    for (int h = 0; h < H; ++h) {
        if (h + 2 < H)      { STAGE_B(h + 1); STAGE_A(h + 2); }
        else if (h + 1 < H) { STAGE_B(h + 1); }
        const int ab = h % 3, bb = h & 1;
        const char* A_ = (const char*)&Ah[ab][0];
        const char* B_ = (const char*)&Bh[bb][0];
        bf16x8 af[8], bf[4];
#pragma unroll
        for (int m = 0; m < 8; ++m) af[m] = *(const bf16x8*)(A_ + aoff[0][m]);
#pragma unroll
        for (int n = 0; n < 4; ++n) bf[n] = *(const bf16x8*)(B_ + boff[0][n]);
        __builtin_amdgcn_s_setprio(1);
#pragma unroll
        for (int n = 0; n < 4; ++n)
#pragma unroll
            for (int m = 0; m < 8; ++m)
                acc[m][n] = __builtin_amdgcn_mfma_f32_16x16x32_bf16(af[m], bf[n], acc[m][n], 0, 0, 0);
        __builtin_amdgcn_s_setprio(0);
#pragma unroll
        for (int m = 0; m < 8; ++m) af[m] = *(const bf16x8*)(A_ + aoff[1][m]);
#pragma unroll
        for (int n = 0; n < 4; ++n) bf[n] = *(const bf16x8*)(B_ + boff[1][n]);
        __builtin_amdgcn_s_setprio(1);
#pragma unroll
        for (int n = 0; n < 4; ++n)
#pragma unroll
            for (int m = 0; m < 8; ++m)
                acc[m][n] = __builtin_amdgcn_mfma_f32_16x16x32_bf16(af[m], bf[n], acc[m][n], 0, 0, 0);
        __builtin_amdgcn_s_setprio(0);
        if (h + 2 < H) { VMCNT(4); } else { VMCNT(0); }
        BARRIER();
    }

    // epilogue: linear bf16 stores into per-slot row buffer
#pragma unroll
    for (int m = 0; m < 8; ++m) {
#pragma unroll
        for (int i = 0; i < 4; ++i) {
            int row  = wr * 128 + m * 16 + hi * 4 + i;
            int grow = m0 + row;
            if (grow < cnt) {
                unsigned short* orow = g2buf + (size_t)(hbase + grow) * DIM + n0 + wc * 64 + lr;
#pragma unroll
                for (int n = 0; n < 4; ++n)
                    orow[n * 16] = f2bf(acc[m][n][i]);
            }
        }
    }
}

// ================= combine: out = w0*r0 + w1*r1 + sh0 + sh1 =================
__global__ __launch_bounds__(256) void combine(
    const unsigned short* __restrict__ g2buf, const int* __restrict__ base,
    const int* __restrict__ se, const int* __restrict__ sp,
    const float* __restrict__ swt, float* __restrict__ out) {
    const int tok = blockIdx.x;
    const int c = threadIdx.x * 8;
    const int e0 = se[2 * tok], e1 = se[2 * tok + 1];
    const float w0 = swt[2 * tok], w1 = swt[2 * tok + 1];
    const size_t r0 = (size_t)(base[e0] + sp[2 * tok]) * DIM + c;
    const size_t r1 = (size_t)(base[e1] + sp[2 * tok + 1]) * DIM + c;
    const size_t r2 = (size_t)(2 * NTOK + tok) * DIM + c;
    const size_t r3 = (size_t)(3 * NTOK + tok) * DIM + c;
    u16x8 a = *(const u16x8*)(g2buf + r0);
    u16x8 b = *(const u16x8*)(g2buf + r1);
    u16x8 s0 = *(const u16x8*)(g2buf + r2);
    u16x8 s1 = *(const u16x8*)(g2buf + r3);
    float o[8];
#pragma unroll
    for (int j = 0; j < 8; ++j)
        o[j] = w0 * bf2f(a[j]) + w1 * bf2f(b[j]) + bf2f(s0[j]) + bf2f(s1[j]);
    float4* op = (float4*)(out + (size_t)tok * DIM + c);
    op[0] = make_float4(o[0], o[1], o[2], o[3]);
    op[1] = make_float4(o[4], o[5], o[6], o[7]);
}

extern "C" void kernel_launch(void* const* d_in, const int* in_sizes, int n_in,
                              void* d_out, int out_size, void* d_ws, size_t ws_size,
                              hipStream_t stream) {
    const float* x   = (const float*)d_in[0];
    const float* gw  = (const float*)d_in[1];
    const float* w1  = (const float*)d_in[2];
    const float* w2  = (const float*)d_in[3];
    const float* w3  = (const float*)d_in[4];
    const float* sw1 = (const float*)d_in[5];
    const float* sw2 = (const float*)d_in[6];
    const float* sw3 = (const float*)d_in[7];
    float* out = (float*)d_out;

    char* ws = (char*)d_ws;
    int*   counts  = (int*)ws;
    int*   basep   = (int*)(ws + 128);
    int*   toklist = (int*)(ws + 4096);               // 512 KB
    int*   se      = (int*)(ws + 4096 + 524288);      // 64 KB
    int*   sp      = (int*)(ws + 4096 + 524288 + 65536);
    float* swt     = (float*)(ws + 4096 + 524288 + 131072);

    unsigned short* hbuf = (unsigned short*)(ws + (2u << 20));

    const size_t hbytes = (size_t)4 * NTOK * INTER * 2;       // 92.3 MB
    const size_t offx   = (2ull << 20) + hbytes;
    const size_t xbytes = (size_t)NTOK * DIM * 2;             // 33.5 MB
    const size_t offw   = offx + xbytes;
    const size_t wB     = (size_t)NEXP * INTER * DIM * 2;     // 92.3 MB
    const size_t swB    = (size_t)SINTER * DIM * 2;           // 11.5 MB

    unsigned short* xb   = (unsigned short*)(ws + offx);
    unsigned short* w1b  = (unsigned short*)(ws + offw);
    unsigned short* w3b  = (unsigned short*)(ws + offw + wB);
    unsigned short* w2b  = (unsigned short*)(ws + offw + 2 * wB);
    unsigned short* sw1b = (unsigned short*)(ws + offw + 3 * wB);
    unsigned short* sw3b = (unsigned short*)(ws + offw + 3 * wB + swB);
    unsigned short* sw2b = (unsigned short*)(ws + offw + 3 * wB + 2 * swB);

    // g2buf (134 MB bf16) aliases xb+w1b+front of w3b — all reads of those
    // regions complete when gemm1 finishes; single-stream ordering => safe.
    unsigned short* g2buf = (unsigned short*)(ws + offx);

    hipMemsetAsync(counts, 0, 64, stream);

    {
        const long long NW = (long long)NEXP * INTER * DIM;
        const long long NS = (long long)SINTER * DIM;
        long long total = 3 * NW + 3 * NS;
        int grid = (int)((total / 8 + 255) / 256);
        cast_all<<<grid, 256, 0, stream>>>(w1, w3, w2, sw1, sw3, sw2,
                                           w1b, w3b, w2b, sw1b, sw3b, sw2b);
    }

    gate_topk<<<NTOK / 4, 256, 0, stream>>>(x, gw, xb, counts, toklist, se, sp, swt);
    prefix_k<<<1, 64, 0, stream>>>(counts, basep);

    gemm1<<<dim3(INTER / 128, NTOK / 256, 18), 512, 0, stream>>>(
        xb, w1b, w3b, sw1b, sw3b, counts, basep, toklist, hbuf);

    gemm2<<<dim3(DIM / 256, NTOK / 256, 18), 512, 0, stream>>>(
        hbuf, w2b, sw2b, counts, basep, g2buf);

    combine<<<NTOK, 256, 0, stream>>>(g2buf, basep, se, sp, swt, out);
}

// Round 14
// 1180.531 us; speedup vs baseline: 1.1185x; 1.1185x over previous
//
#include <hip/hip_runtime.h>
#include <hip/hip_bf16.h>

#define DIM 2048
#define INTER 1408
#define NEXP 16
#define NTOK 8192
#define SINTER 2816

typedef __attribute__((ext_vector_type(8))) short bf16x8;
typedef __attribute__((ext_vector_type(4))) float f32x4;
typedef __attribute__((ext_vector_type(4))) unsigned short u16x4;
typedef __attribute__((ext_vector_type(8))) unsigned short u16x8;

#define VMCNT(n) asm volatile("s_waitcnt vmcnt(" #n ")" ::: "memory")
#define BARRIER() __builtin_amdgcn_s_barrier()

__device__ __forceinline__ unsigned short f2bf(float f) {
    union { float f; unsigned u; } a; a.f = f;
    unsigned r = a.u + 0x7fffu + ((a.u >> 16) & 1u);
    return (unsigned short)(r >> 16);
}
__device__ __forceinline__ float bf2f(unsigned short u) {
    union { unsigned u; float f; } a; a.u = ((unsigned)u) << 16; return a.f;
}

__device__ __forceinline__ void gload16(const void* g, void* lds) {
    __builtin_amdgcn_global_load_lds(
        (const __attribute__((address_space(1))) void*)g,
        (__attribute__((address_space(3))) void*)lds, 16, 0, 0);
}

// ---------------- one-shot f32 -> bf16 cast of ALL weight tensors ----------------
__global__ __launch_bounds__(256) void cast_all(
    const float* __restrict__ w1, const float* __restrict__ w3,
    const float* __restrict__ w2, const float* __restrict__ sw1,
    const float* __restrict__ sw3, const float* __restrict__ sw2,
    unsigned short* __restrict__ w1b, unsigned short* __restrict__ w3b,
    unsigned short* __restrict__ w2b, unsigned short* __restrict__ sw1b,
    unsigned short* __restrict__ sw3b, unsigned short* __restrict__ sw2b) {
    const long long NW = (long long)NEXP * INTER * DIM;
    const long long NS = (long long)SINTER * DIM;
    long long i = ((long long)blockIdx.x * 256 + threadIdx.x) * 8;
    const float* s; unsigned short* d; long long off;
    if      (i < NW)            { s = w1;  d = w1b;  off = i; }
    else if (i < 2 * NW)        { s = w3;  d = w3b;  off = i - NW; }
    else if (i < 3 * NW)        { s = w2;  d = w2b;  off = i - 2 * NW; }
    else if (i < 3 * NW + NS)   { s = sw1; d = sw1b; off = i - 3 * NW; }
    else if (i < 3 * NW + 2*NS) { s = sw3; d = sw3b; off = i - 3 * NW - NS; }
    else if (i < 3 * NW + 3*NS) { s = sw2; d = sw2b; off = i - 3 * NW - 2 * NS; }
    else return;
    float4 a = *(const float4*)(s + off), b = *(const float4*)(s + off + 4);
    u16x8 o = { f2bf(a.x), f2bf(a.y), f2bf(a.z), f2bf(a.w),
                f2bf(b.x), f2bf(b.y), f2bf(b.z), f2bf(b.w) };
    *(u16x8*)(d + off) = o;
}

// ---------------- gate + top2 routing (+ x -> bf16 cast fused) ----------------
__global__ __launch_bounds__(256) void gate_topk(
    const float* __restrict__ x, const float* __restrict__ gw,
    unsigned short* __restrict__ xb,
    int* __restrict__ counts, int* __restrict__ toklist,
    int* __restrict__ se, int* __restrict__ sp, float* __restrict__ swt) {
    int wave = threadIdx.x >> 6;
    int lane = threadIdx.x & 63;
    int tok  = blockIdx.x * 4 + wave;
    const float* xr = x + (size_t)tok * DIM;
    unsigned short* xbr = xb + (size_t)tok * DIM;

    float part[NEXP];
#pragma unroll
    for (int e = 0; e < NEXP; ++e) part[e] = 0.f;
#pragma unroll
    for (int c = 0; c < DIM / 256; ++c) {
        float4 xv = *(const float4*)(xr + c * 256 + lane * 4);
        u16x4 xo = { f2bf(xv.x), f2bf(xv.y), f2bf(xv.z), f2bf(xv.w) };
        *(u16x4*)(xbr + c * 256 + lane * 4) = xo;
#pragma unroll
        for (int e = 0; e < NEXP; ++e) {
            float4 g = *(const float4*)(gw + e * DIM + c * 256 + lane * 4);
            part[e] += xv.x * g.x + xv.y * g.y + xv.z * g.z + xv.w * g.w;
        }
    }
#pragma unroll
    for (int e = 0; e < NEXP; ++e) {
        float v = part[e];
#pragma unroll
        for (int off = 32; off; off >>= 1) v += __shfl_xor(v, off);
        part[e] = v;
    }
    float mx = part[0];
#pragma unroll
    for (int e = 1; e < NEXP; ++e) mx = fmaxf(mx, part[e]);
    float Z = 0.f;
#pragma unroll
    for (int e = 0; e < NEXP; ++e) Z += expf(part[e] - mx);
    int i1 = 0; float m1 = part[0];
#pragma unroll
    for (int e = 1; e < NEXP; ++e) if (part[e] > m1) { m1 = part[e]; i1 = e; }
    int i2 = -1; float m2 = -1e30f;
#pragma unroll
    for (int e = 0; e < NEXP; ++e) if (e != i1 && part[e] > m2) { m2 = part[e]; i2 = e; }
    if (lane == 0) {
        float w1v = expf(m1 - mx) / Z;
        float w2v = expf(m2 - mx) / Z;
        int p1 = atomicAdd(&counts[i1], 1);
        toklist[i1 * NTOK + p1] = tok;
        int p2 = atomicAdd(&counts[i2], 1);
        toklist[i2 * NTOK + p2] = tok;
        se[2 * tok] = i1;  sp[2 * tok] = p1;  swt[2 * tok] = w1v;
        se[2 * tok + 1] = i2;  sp[2 * tok + 1] = p2;  swt[2 * tok + 1] = w2v;
    }
}

__global__ void prefix_k(const int* __restrict__ counts, int* __restrict__ base) {
    if (threadIdx.x == 0) {
        int acc = 0;
        for (int e = 0; e < NEXP; ++e) { base[e] = acc; acc += counts[e]; }
        base[16] = acc;          // == 2*NTOK
        base[17] = acc + NTOK;
    }
}

// ================= GEMM1: h = silu(X W1^T) * (X W3^T) =================
// r11-exact (best measured: 462 us): tile 256x128, BK=64, 2 LDS buffers,
// stage(h+1) issued under MFMA, vmcnt(0)+1 barrier per step, (512,2).
// DO NOT restructure: ping-pong (r3), counted-vmcnt multi-phase (r2),
// asymmetric depth (r12), occupancy raise (r10) all measured WORSE.
__global__ __launch_bounds__(512, 2) void gemm1(
    const unsigned short* __restrict__ xb,
    const unsigned short* __restrict__ w1b, const unsigned short* __restrict__ w3b,
    const unsigned short* __restrict__ sw1b, const unsigned short* __restrict__ sw3b,
    const int* __restrict__ counts, const int* __restrict__ base,
    const int* __restrict__ toklist, unsigned short* __restrict__ hbuf) {
    const int e   = blockIdx.z;
    const int cnt = (e < NEXP) ? counts[e] : NTOK;
    const int m0  = blockIdx.y * 256;
    if (m0 >= cnt) return;
    const int n0  = blockIdx.x * 128;
    const size_t woff = (size_t)((e < NEXP) ? e : e - NEXP) * INTER * DIM;
    const unsigned short* B1 = ((e < NEXP) ? w1b : sw1b) + woff;
    const unsigned short* B3 = ((e < NEXP) ? w3b : sw3b) + woff;
    const int hbase = base[e];
    const int* tl = toklist + e * NTOK;

    __shared__ __attribute__((aligned(16))) unsigned short As[2][16384];  // 64 KB
    __shared__ __attribute__((aligned(16))) unsigned short B1s[2][8192];  // 32 KB
    __shared__ __attribute__((aligned(16))) unsigned short B3s[2][8192];  // 32 KB

    const int tid = threadIdx.x;
    const int w = tid >> 6, lu = tid & 63;
    const int wr = w >> 1, wc = w & 1;
    const int lr = lu & 15, hi = lu >> 4;

    const int srow = tid >> 3;
    const int sslot = tid & 7;
    const int cEl = ((sslot ^ (srow & 7)) * 8);

    const unsigned short* aSrc[4];
#pragma unroll
    for (int i = 0; i < 4; ++i) {
        int grow = m0 + 64 * i + srow;
        int t;
        if (e < NEXP) t = (grow < cnt) ? tl[grow] : 0;
        else          t = grow;
        aSrc[i] = xb + (size_t)t * DIM + cEl;
    }
    const unsigned short *b1Src[2], *b3Src[2];
#pragma unroll
    for (int i = 0; i < 2; ++i) {
        int r = n0 + 64 * i + srow;
        b1Src[i] = B1 + (size_t)r * DIM + cEl;
        b3Src[i] = B3 + (size_t)r * DIM + cEl;
    }

    int aoff[2][4], boff[2][4];
#pragma unroll
    for (int kk = 0; kk < 2; ++kk) {
#pragma unroll
        for (int m = 0; m < 4; ++m) {
            int R = wr * 64 + m * 16 + lr;
            aoff[kk][m] = R * 128 + (((kk * 4 + hi) ^ (lr & 7)) << 4);
        }
#pragma unroll
        for (int n = 0; n < 4; ++n) {
            int R = wc * 64 + n * 16 + lr;
            boff[kk][n] = R * 128 + (((kk * 4 + hi) ^ (lr & 7)) << 4);
        }
    }

    f32x4 acc1[4][4], acc3[4][4];
#pragma unroll
    for (int m = 0; m < 4; ++m)
#pragma unroll
        for (int n = 0; n < 4; ++n) {
            acc1[m][n] = (f32x4){0.f, 0.f, 0.f, 0.f};
            acc3[m][n] = (f32x4){0.f, 0.f, 0.f, 0.f};
        }

    const int H = DIM / 64;   // 32 steps

    auto STAGE = [&](int hh) {
        int hb = hh & 1;
        int kc = hh * 64;
#pragma unroll
        for (int i = 0; i < 4; ++i)
            gload16(aSrc[i] + kc, &As[hb][i * 4096 + tid * 8]);
#pragma unroll
        for (int i = 0; i < 2; ++i) {
            gload16(b1Src[i] + kc, &B1s[hb][i * 4096 + tid * 8]);
            gload16(b3Src[i] + kc, &B3s[hb][i * 4096 + tid * 8]);
        }
    };

    STAGE(0);
    VMCNT(0);
    BARRIER();

    for (int h = 0; h < H; ++h) {
        const int hb = h & 1;
        const char* As_ = (const char*)&As[hb][0];
        const char* B1_ = (const char*)&B1s[hb][0];
        const char* B3_ = (const char*)&B3s[hb][0];
        bf16x8 af[4], b1f[4], b3f[4];
#pragma unroll
        for (int m = 0; m < 4; ++m) af[m] = *(const bf16x8*)(As_ + aoff[0][m]);
#pragma unroll
        for (int n = 0; n < 4; ++n) {
            b1f[n] = *(const bf16x8*)(B1_ + boff[0][n]);
            b3f[n] = *(const bf16x8*)(B3_ + boff[0][n]);
        }
        if (h + 1 < H) STAGE(h + 1);   // other buffer; lands under MFMA
        __builtin_amdgcn_s_setprio(1);
#pragma unroll
        for (int n = 0; n < 4; ++n)
#pragma unroll
            for (int m = 0; m < 4; ++m)
                acc1[m][n] = __builtin_amdgcn_mfma_f32_16x16x32_bf16(af[m], b1f[n], acc1[m][n], 0, 0, 0);
#pragma unroll
        for (int n = 0; n < 4; ++n)
#pragma unroll
            for (int m = 0; m < 4; ++m)
                acc3[m][n] = __builtin_amdgcn_mfma_f32_16x16x32_bf16(af[m], b3f[n], acc3[m][n], 0, 0, 0);
        __builtin_amdgcn_s_setprio(0);
#pragma unroll
        for (int m = 0; m < 4; ++m) af[m] = *(const bf16x8*)(As_ + aoff[1][m]);
#pragma unroll
        for (int n = 0; n < 4; ++n) {
            b1f[n] = *(const bf16x8*)(B1_ + boff[1][n]);
            b3f[n] = *(const bf16x8*)(B3_ + boff[1][n]);
        }
        __builtin_amdgcn_s_setprio(1);
#pragma unroll
        for (int n = 0; n < 4; ++n)
#pragma unroll
            for (int m = 0; m < 4; ++m)
                acc1[m][n] = __builtin_amdgcn_mfma_f32_16x16x32_bf16(af[m], b1f[n], acc1[m][n], 0, 0, 0);
#pragma unroll
        for (int n = 0; n < 4; ++n)
#pragma unroll
            for (int m = 0; m < 4; ++m)
                acc3[m][n] = __builtin_amdgcn_mfma_f32_16x16x32_bf16(af[m], b3f[n], acc3[m][n], 0, 0, 0);
        __builtin_amdgcn_s_setprio(0);
        VMCNT(0);
        BARRIER();
    }

    // epilogue: h = silu(c1)*c3 -> bf16 scratch
#pragma unroll
    for (int m = 0; m < 4; ++m) {
#pragma unroll
        for (int i = 0; i < 4; ++i) {
            int row  = wr * 64 + m * 16 + hi * 4 + i;
            int grow = m0 + row;
            if (grow < cnt) {
                size_t ro = (size_t)(hbase + grow) * INTER;
#pragma unroll
                for (int n = 0; n < 4; ++n) {
                    int col = n0 + wc * 64 + n * 16 + lr;
                    float a = acc1[m][n][i];
                    float hv = a / (1.f + __expf(-a)) * acc3[m][n][i];
                    hbuf[ro + col] = f2bf(hv);
                }
            }
        }
    }
}

// ================= GEMM2: g2buf = h W2^T (linear bf16 rows) =================
// r11-exact: tile 256x256, BK=64, 2-buffer depth-1, 8 waves 2Mx4N.
__global__ __launch_bounds__(512, 2) void gemm2(
    const unsigned short* __restrict__ hbuf,
    const unsigned short* __restrict__ w2b, const unsigned short* __restrict__ sw2b,
    const int* __restrict__ counts, const int* __restrict__ base,
    unsigned short* __restrict__ g2buf) {
    const int e   = blockIdx.z;
    const int cnt = (e < NEXP) ? counts[e] : NTOK;
    const int m0  = blockIdx.y * 256;
    if (m0 >= cnt) return;
    const int n0  = blockIdx.x * 256;
    const int hbase = base[e];
    const size_t bstride = (e < NEXP) ? INTER : SINTER;
    const unsigned short* Bb = (e < NEXP) ? w2b + (size_t)e * DIM * INTER
                                          : sw2b + (size_t)(e - NEXP) * INTER;

    __shared__ __attribute__((aligned(16))) unsigned short Ah[2][16384];  // 64 KB
    __shared__ __attribute__((aligned(16))) unsigned short Bh[2][16384];  // 64 KB

    const int tid = threadIdx.x;
    const int w = tid >> 6, lu = tid & 63;
    const int wr = w >> 2, wc = w & 3;
    const int lr = lu & 15, hi = lu >> 4;

    const int srow = tid >> 3;
    const int sslot = tid & 7;
    const int cEl = ((sslot ^ (srow & 7)) * 8);

    const unsigned short* aSrc[4];
#pragma unroll
    for (int i = 0; i < 4; ++i)
        aSrc[i] = hbuf + (size_t)(hbase + m0 + 64 * i + srow) * INTER + cEl;
    const unsigned short* bSrc[4];
#pragma unroll
    for (int i = 0; i < 4; ++i)
        bSrc[i] = Bb + (size_t)(n0 + 64 * i + srow) * bstride + cEl;

    int aoff[2][8], boff[2][4];
#pragma unroll
    for (int kk = 0; kk < 2; ++kk) {
#pragma unroll
        for (int m = 0; m < 8; ++m) {
            int R = wr * 128 + m * 16 + lr;
            aoff[kk][m] = R * 128 + (((kk * 4 + hi) ^ (lr & 7)) << 4);
        }
#pragma unroll
        for (int n = 0; n < 4; ++n) {
            int R = wc * 64 + n * 16 + lr;
            boff[kk][n] = R * 128 + (((kk * 4 + hi) ^ (lr & 7)) << 4);
        }
    }

    f32x4 acc[8][4];
#pragma unroll
    for (int m = 0; m < 8; ++m)
#pragma unroll
        for (int n = 0; n < 4; ++n) acc[m][n] = (f32x4){0.f, 0.f, 0.f, 0.f};

    const int H = INTER / 64;   // 22 steps

    auto STAGE = [&](int hh) {
        int hb = hh & 1;
        int kc = hh * 64;
#pragma unroll
        for (int i = 0; i < 4; ++i)
            gload16(aSrc[i] + kc, &Ah[hb][i * 4096 + tid * 8]);
#pragma unroll
        for (int i = 0; i < 4; ++i)
            gload16(bSrc[i] + kc, &Bh[hb][i * 4096 + tid * 8]);
    };

    STAGE(0);
    VMCNT(0);
    BARRIER();

    for (int h = 0; h < H; ++h) {
        const int hb = h & 1;
        const char* A_ = (const char*)&Ah[hb][0];
        const char* B_ = (const char*)&Bh[hb][0];
        bf16x8 af[8], bf[4];
#pragma unroll
        for (int m = 0; m < 8; ++m) af[m] = *(const bf16x8*)(A_ + aoff[0][m]);
#pragma unroll
        for (int n = 0; n < 4; ++n) bf[n] = *(const bf16x8*)(B_ + boff[0][n]);
        if (h + 1 < H) STAGE(h + 1);   // other buffer; lands under MFMA
        __builtin_amdgcn_s_setprio(1);
#pragma unroll
        for (int n = 0; n < 4; ++n)
#pragma unroll
            for (int m = 0; m < 8; ++m)
                acc[m][n] = __builtin_amdgcn_mfma_f32_16x16x32_bf16(af[m], bf[n], acc[m][n], 0, 0, 0);
        __builtin_amdgcn_s_setprio(0);
#pragma unroll
        for (int m = 0; m < 8; ++m) af[m] = *(const bf16x8*)(A_ + aoff[1][m]);
#pragma unroll
        for (int n = 0; n < 4; ++n) bf[n] = *(const bf16x8*)(B_ + boff[1][n]);
        __builtin_amdgcn_s_setprio(1);
#pragma unroll
        for (int n = 0; n < 4; ++n)
#pragma unroll
            for (int m = 0; m < 8; ++m)
                acc[m][n] = __builtin_amdgcn_mfma_f32_16x16x32_bf16(af[m], bf[n], acc[m][n], 0, 0, 0);
        __builtin_amdgcn_s_setprio(0);
        VMCNT(0);
        BARRIER();
    }

    // epilogue: linear bf16 stores into per-slot row buffer
#pragma unroll
    for (int m = 0; m < 8; ++m) {
#pragma unroll
        for (int i = 0; i < 4; ++i) {
            int row  = wr * 128 + m * 16 + hi * 4 + i;
            int grow = m0 + row;
            if (grow < cnt) {
                unsigned short* orow = g2buf + (size_t)(hbase + grow) * DIM + n0 + wc * 64 + lr;
#pragma unroll
                for (int n = 0; n < 4; ++n)
                    orow[n * 16] = f2bf(acc[m][n][i]);
            }
        }
    }
}

// ================= combine: out = w0*r0 + w1*r1 + sh0 + sh1 =================
__global__ __launch_bounds__(256) void combine(
    const unsigned short* __restrict__ g2buf, const int* __restrict__ base,
    const int* __restrict__ se, const int* __restrict__ sp,
    const float* __restrict__ swt, float* __restrict__ out) {
    const int tok = blockIdx.x;
    const int c = threadIdx.x * 8;
    const int e0 = se[2 * tok], e1 = se[2 * tok + 1];
    const float w0 = swt[2 * tok], w1 = swt[2 * tok + 1];
    const size_t r0 = (size_t)(base[e0] + sp[2 * tok]) * DIM + c;
    const size_t r1 = (size_t)(base[e1] + sp[2 * tok + 1]) * DIM + c;
    const size_t r2 = (size_t)(2 * NTOK + tok) * DIM + c;
    const size_t r3 = (size_t)(3 * NTOK + tok) * DIM + c;
    u16x8 a = *(const u16x8*)(g2buf + r0);
    u16x8 b = *(const u16x8*)(g2buf + r1);
    u16x8 s0 = *(const u16x8*)(g2buf + r2);
    u16x8 s1 = *(const u16x8*)(g2buf + r3);
    float o[8];
#pragma unroll
    for (int j = 0; j < 8; ++j)
        o[j] = w0 * bf2f(a[j]) + w1 * bf2f(b[j]) + bf2f(s0[j]) + bf2f(s1[j]);
    float4* op = (float4*)(out + (size_t)tok * DIM + c);
    op[0] = make_float4(o[0], o[1], o[2], o[3]);
    op[1] = make_float4(o[4], o[5], o[6], o[7]);
}

extern "C" void kernel_launch(void* const* d_in, const int* in_sizes, int n_in,
                              void* d_out, int out_size, void* d_ws, size_t ws_size,
                              hipStream_t stream) {
    const float* x   = (const float*)d_in[0];
    const float* gw  = (const float*)d_in[1];
    const float* w1  = (const float*)d_in[2];
    const float* w2  = (const float*)d_in[3];
    const float* w3  = (const float*)d_in[4];
    const float* sw1 = (const float*)d_in[5];
    const float* sw2 = (const float*)d_in[6];
    const float* sw3 = (const float*)d_in[7];
    float* out = (float*)d_out;

    char* ws = (char*)d_ws;
    int*   counts  = (int*)ws;
    int*   basep   = (int*)(ws + 128);
    int*   toklist = (int*)(ws + 4096);               // 512 KB
    int*   se      = (int*)(ws + 4096 + 524288);      // 64 KB
    int*   sp      = (int*)(ws + 4096 + 524288 + 65536);
    float* swt     = (float*)(ws + 4096 + 524288 + 131072);

    unsigned short* hbuf = (unsigned short*)(ws + (2u << 20));

    const size_t hbytes = (size_t)4 * NTOK * INTER * 2;       // 92.3 MB
    const size_t offx   = (2ull << 20) + hbytes;
    const size_t xbytes = (size_t)NTOK * DIM * 2;             // 33.5 MB
    const size_t offw   = offx + xbytes;
    const size_t wB     = (size_t)NEXP * INTER * DIM * 2;     // 92.3 MB
    const size_t swB    = (size_t)SINTER * DIM * 2;           // 11.5 MB

    unsigned short* xb   = (unsigned short*)(ws + offx);
    unsigned short* w1b  = (unsigned short*)(ws + offw);
    unsigned short* w3b  = (unsigned short*)(ws + offw + wB);
    unsigned short* w2b  = (unsigned short*)(ws + offw + 2 * wB);
    unsigned short* sw1b = (unsigned short*)(ws + offw + 3 * wB);
    unsigned short* sw3b = (unsigned short*)(ws + offw + 3 * wB + swB);
    unsigned short* sw2b = (unsigned short*)(ws + offw + 3 * wB + 2 * swB);

    // g2buf (134 MB bf16) aliases xb+w1b+front of w3b — all reads of those
    // regions complete when gemm1 finishes; single-stream ordering => safe.
    unsigned short* g2buf = (unsigned short*)(ws + offx);

    hipMemsetAsync(counts, 0, 64, stream);

    {
        const long long NW = (long long)NEXP * INTER * DIM;
        const long long NS = (long long)SINTER * DIM;
        long long total = 3 * NW + 3 * NS;
        int grid = (int)((total / 8 + 255) / 256);
        cast_all<<<grid, 256, 0, stream>>>(w1, w3, w2, sw1, sw3, sw2,
                                           w1b, w3b, w2b, sw1b, sw3b, sw2b);
    }

    gate_topk<<<NTOK / 4, 256, 0, stream>>>(x, gw, xb, counts, toklist, se, sp, swt);
    prefix_k<<<1, 64, 0, stream>>>(counts, basep);

    gemm1<<<dim3(INTER / 128, NTOK / 256, 18), 512, 0, stream>>>(
        xb, w1b, w3b, sw1b, sw3b, counts, basep, toklist, hbuf);

    gemm2<<<dim3(DIM / 256, NTOK / 256, 18), 512, 0, stream>>>(
        hbuf, w2b, sw2b, counts, basep, g2buf);

    combine<<<NTOK, 256, 0, stream>>>(g2buf, basep, se, sp, swt, out);
}